// Round 13
// baseline (62.032 us; speedup 1.0000x reference)
//
#include <hip/hip_runtime.h>
#include <stdint.h>

#pragma clang fp contract(off)

// PRNG: jax_threefry_partitionable 32-bit random_bits = o0 ^ o1 (VERIFIED round 3)
// r8=57.5 (K1 iou+pack -> K2 select + FULL 110MB write). r12 K2-occupancy fix:
// 60.5 (worse; spills). r13: move the 110MB write INTO K1 as fire-and-forget
// ZERO-stores overlapping the VALU-bound IoU loop (mem pipe idle there);
// K2 shrinks to selection + <=8K-element scatter (r5-proven structure).

#define BB 64
#define NN 4096
#define MM 128
#define LL 21
#define NTOT (BB * NN)                           // 262144 rois
#define DELTA_ELEMS ((size_t)BB * NN * LL * 4)   // 22020096 floats

__host__ __device__ __forceinline__ uint32_t rotl32(uint32_t v, int s) {
  return (v << s) | (v >> (32 - s));
}

// Threefry-2x32, 20 rounds (JAX's threefry2x32).
__host__ __device__ inline void threefry2x32(uint32_t k0, uint32_t k1,
                                             uint32_t x0, uint32_t x1,
                                             uint32_t* o0, uint32_t* o1) {
  const uint32_t ks2 = k0 ^ k1 ^ 0x1BD11BDAu;
  x0 += k0; x1 += k1;
#define TF_R(r) do { x0 += x1; x1 = rotl32(x1, (r)); x1 ^= x0; } while (0)
  TF_R(13); TF_R(15); TF_R(26); TF_R(6);
  x0 += k1;  x1 += ks2 + 1u;
  TF_R(17); TF_R(29); TF_R(16); TF_R(24);
  x0 += ks2; x1 += k0 + 2u;
  TF_R(13); TF_R(15); TF_R(26); TF_R(6);
  x0 += k0;  x1 += k1 + 3u;
  TF_R(17); TF_R(29); TF_R(16); TF_R(24);
  x0 += k1;  x1 += ks2 + 4u;
  TF_R(13); TF_R(15); TF_R(26); TF_R(6);
  x0 += ks2; x1 += k0 + 5u;
#undef TF_R
  *o0 = x0; *o1 = x1;
}

__device__ __forceinline__ uint32_t jax_bits32(uint32_t ka, uint32_t kb, uint32_t idx) {
  uint32_t o0, o1;
  threefry2x32(ka, kb, 0u, idx, &o0, &o1);   // counter (hi=0, lo=idx)
  return o0 ^ o1;                            // partitionable 32-bit fold
}

// jax.random.randint(key, (B,N), 1, 1280): span=1279, mult=(2^16%1279)^2%1279=882
__device__ __forceinline__ uint32_t jax_randint_1_1280(uint32_t k1a, uint32_t k1b,
                                                       uint32_t k2a, uint32_t k2b,
                                                       uint32_t idx) {
  const uint32_t hi = jax_bits32(k1a, k1b, idx);
  const uint32_t lo = jax_bits32(k2a, k2b, idx);
  const uint32_t off = ((hi % 1279u) * 882u + (lo % 1279u)) % 1279u;
  return 1u + off;
}

__device__ __forceinline__ float4 compute_delta(const float4 r, const float4 g) {
  float bh = r.z - r.x, bw = r.w - r.y;
  const float bcy = r.x + 0.5f * bh, bcx = r.y + 0.5f * bw;
  const float gh = g.z - g.x, gw = g.w - g.y;
  const float gcy = g.x + 0.5f * gh, gcx = g.y + 0.5f * gw;
  if (bw == 0.0f) bw = 1e-3f;
  if (bh == 0.0f) bh = 1e-3f;
  const float dx = (gcx - bcx) / bw;
  const float dy = (gcy - bcy) / bh;
  const float dw = (gw == 0.0f) ? 0.0f : logf(gw / bw);
  const float dh = (gh == 0.0f) ? 0.0f : logf(gh / bh);
  float4 dv;
  dv.x = dy / 0.1f; dv.y = dx / 0.1f; dv.z = dh / 0.2f; dv.w = dw / 0.2f;
  return dv;
}

// ---------- K1: zero-write own output region + IoU argmax + randint pack ----------
// The 27 float4 zero-stores are issued before the VALU-bound IoU loop and drain
// on the otherwise-idle memory pipe underneath it.
__global__ __launch_bounds__(256) void iou_zero_pack_kernel(
    const float* __restrict__ roi, const float* __restrict__ gt,
    uint32_t* __restrict__ packed, float* __restrict__ out,
    uint32_t k1a, uint32_t k1b, uint32_t k2a, uint32_t k2b) {
  __shared__ float4 gtb[MM];
  __shared__ float gar[MM];
  const int b = blockIdx.y;
  const int t = threadIdx.x;
  const int ri0 = blockIdx.x * 256;            // in-row base roi of this block
  const int i = b * NN + ri0 + t;
  const float4 r = ((const float4*)roi)[i];    // [y1,x1,y2,x2]
  if (t < MM) {
    const float4 g = ((const float4*)gt)[b * MM + t];
    gtb[t] = g;
    gar[t] = (g.z - g.x) * (g.w - g.y);
  }
  __syncthreads();

  // ---- fire-and-forget zero stores for this block's 256-roi output region ----
  const float4 z = {0.f, 0.f, 0.f, 0.f};
  const size_t gri0 = (size_t)b * NN + ri0;
  float4* dbase = (float4*)out + gri0 * LL;            // 5376 float4
  #pragma unroll
  for (int k = 0; k < LL; ++k) dbase[t + k * 256] = z;
  float4* lbase = (float4*)(out + DELTA_ELEMS) + gri0 * LL / 4;  // 1344 float4
  #pragma unroll
  for (int q = 0; q < 5; ++q) lbase[t + q * 256] = z;
  if (t < 1344 - 5 * 256) lbase[t + 5 * 256] = z;

  // ---- VALU-bound IoU loop (stores drain underneath) ----
  const float barea = (r.z - r.x) * (r.w - r.y);
  float best = -1.0f;
  int bm = 0;
  for (int m = 0; m < MM; ++m) {
    const float4 g = gtb[m];
    const float xt = fmaxf(r.y, g.y);
    const float yt = fmaxf(r.x, g.x);
    const float xb = fminf(r.w, g.w);
    const float yb = fminf(r.z, g.z);
    const float inter = fmaxf(xb - xt, 0.0f) * fmaxf(yb - yt, 0.0f);
    const float uni = (barea + gar[m]) - inter;
    const float iou = inter / uni;                    // IEEE div, bit-exact vs ref
    if (iou > best) { best = iou; bm = m; }           // first-occurrence argmax
  }
  const uint32_t rnd = jax_randint_1_1280(k1a, k1b, k2a, k2b, (uint32_t)i);
  packed[i] = (uint32_t)bm | ((best > 0.5f) ? (rnd << 7) : 0u);
}

// ---------- K2: per-row selection + tiny nonzero scatter (r5-proven form) ----------
__global__ __launch_bounds__(256) void select_scatter_kernel(
    const float* __restrict__ roi, const float* __restrict__ gt,
    const int* __restrict__ glab, const uint32_t* __restrict__ packed,
    float* __restrict__ out) {
  __shared__ uint32_t hist[1280];
  __shared__ uint32_t scan[256];
  __shared__ int s_thr;
  __shared__ int s_take;
  const int b = blockIdx.x;
  const int t = threadIdx.x;
  for (int j = t; j < 1280; j += 256) hist[j] = 0u;
  if (t == 0) { s_thr = 0; s_take = 0; }
  __syncthreads();

  // thread t owns row rois t*16..t*16+15 (tie order!)
  uint32_t rv[16];
  const uint4* p4 = (const uint4*)(packed + (size_t)b * NN);
  #pragma unroll
  for (int q = 0; q < 4; ++q) {
    const uint4 w = p4[t * 4 + q];
    rv[q * 4 + 0] = w.x >> 7;
    rv[q * 4 + 1] = w.y >> 7;
    rv[q * 4 + 2] = w.z >> 7;
    rv[q * 4 + 3] = w.w >> 7;
  }
  #pragma unroll
  for (int k = 0; k < 16; ++k)
    if (rv[k]) atomicAdd(&hist[rv[k]], 1u);
  __syncthreads();

  // suffix sums over 5-bin chunks: scan[t] = sum_{j>=t*5} hist[j]
  uint32_t chunk = 0;
  #pragma unroll
  for (int j = 0; j < 5; ++j) chunk += hist[t * 5 + j];
  scan[t] = chunk;
  __syncthreads();
  for (int off = 1; off < 256; off <<= 1) {
    const uint32_t v = (t + off < 256) ? scan[t + off] : 0u;
    __syncthreads();
    scan[t] += v;
    __syncthreads();
  }
  const uint32_t total = scan[0];
  if (total > 128u) {
    const uint32_t Sc = scan[t];
    const uint32_t Sn = (t < 255) ? scan[t + 1] : 0u;
    if (Sc >= 128u && Sn < 128u) {       // threshold bin lives in my chunk
      uint32_t s = Sn;
      #pragma unroll
      for (int j = 4; j >= 0; --j) {
        const uint32_t h = hist[t * 5 + j];
        if (s + h >= 128u) { s_thr = t * 5 + j; s_take = 128 - (int)s; break; }
        s += h;
      }
    }
  }
  __syncthreads();
  const uint32_t thr = (uint32_t)s_thr;
  const uint32_t take = (uint32_t)s_take;

  // exclusive prefix of tie counts (ascending index)
  uint32_t lt = 0;
  if (thr > 0) {
    #pragma unroll
    for (int k = 0; k < 16; ++k) lt += (rv[k] == thr) ? 1u : 0u;
  }
  scan[t] = lt;
  __syncthreads();
  for (int off = 1; off < 256; off <<= 1) {
    const uint32_t v = (t >= off) ? scan[t - off] : 0u;
    __syncthreads();
    scan[t] += v;
    __syncthreads();
  }
  uint32_t run = scan[t] - lt;           // exclusive prefix of ties before me

  // selected rois (<=128/row): compute delta + scatter the 2 nonzero stores
  #pragma unroll
  for (int k = 0; k < 16; ++k) {
    bool s;
    if (thr == 0) {                      // total <= 128: keep all masked
      s = rv[k] > 0u;
    } else {
      s = (rv[k] > thr);
      if (rv[k] == thr) { s = (run < take); ++run; }
    }
    if (s) {
      const int i = b * NN + t * 16 + k;
      const int mi = (int)(packed[i] & 127u);
      const float4 r = ((const float4*)roi)[i];
      const float4 g = ((const float4*)gt)[b * MM + mi];
      const int lbl = glab[b * MM + mi];
      const float4 dv = compute_delta(r, g);
      ((float4*)out)[(size_t)i * LL + lbl] = dv;              // delta one-hot row
      out[DELTA_ELEMS + (size_t)i * LL + lbl] = 1.0f;         // label one-hot
    }
  }
}

// ================= Slots-mode fallback (r4 proven, ws too small) =================
__global__ __launch_bounds__(256) void iou_kernel_s(const float* __restrict__ roi,
                                                    const float* __restrict__ gt,
                                                    int* __restrict__ midx,
                                                    float* __restrict__ merged) {
  __shared__ float4 gtb[MM];
  const int b = blockIdx.y;
  const int t = threadIdx.x;
  if (t < MM) gtb[t] = ((const float4*)gt)[b * MM + t];
  __syncthreads();
  const int i = b * NN + blockIdx.x * 256 + t;
  const float4 r = ((const float4*)roi)[i];
  const float barea = (r.z - r.x) * (r.w - r.y);
  float best = -1.0f;
  int bm = 0;
  for (int m = 0; m < MM; ++m) {
    const float4 g = gtb[m];
    const float garea = (g.z - g.x) * (g.w - g.y);
    const float xt = fmaxf(r.y, g.y);
    const float yt = fmaxf(r.x, g.x);
    const float xb = fminf(r.w, g.w);
    const float yb = fminf(r.z, g.z);
    const float inter = fmaxf(xb - xt, 0.0f) * fmaxf(yb - yt, 0.0f);
    const float iou = inter / ((barea + garea) - inter);
    if (iou > best) { best = iou; bm = m; }
  }
  midx[(size_t)i * 84] = bm;
  merged[(size_t)i * 84] = best;
}

__global__ __launch_bounds__(256) void select_kernel_s(const float* __restrict__ merged,
                                                       int* __restrict__ sel,
                                                       uint32_t k1a, uint32_t k1b,
                                                       uint32_t k2a, uint32_t k2b) {
  __shared__ uint32_t buf[NN];
  __shared__ uint32_t hist[1280];
  __shared__ uint32_t scan[256];
  __shared__ int s_thr;
  __shared__ int s_take;
  const int b = blockIdx.x;
  const int t = threadIdx.x;
  for (int j = t; j < 1280; j += 256) hist[j] = 0u;
  if (t == 0) { s_thr = 0; s_take = 0; }
  #pragma unroll
  for (int k = 0; k < 16; ++k) {
    const int li = t + k * 256;
    buf[li] = __float_as_uint(merged[(size_t)(b * NN + li) * 84]);
  }
  __syncthreads();
  uint32_t rv[16];
  const int lbase = t * 16;
  #pragma unroll
  for (int k = 0; k < 16; ++k) {
    const int li = lbase + k;
    uint32_t r = 0u;
    if (__uint_as_float(buf[li]) > 0.5f) {
      r = jax_randint_1_1280(k1a, k1b, k2a, k2b, (uint32_t)(b * NN + li));
      atomicAdd(&hist[r], 1u);
    }
    rv[k] = r;
  }
  __syncthreads();
  uint32_t chunk = 0;
  #pragma unroll
  for (int j = 0; j < 5; ++j) chunk += hist[t * 5 + j];
  scan[t] = chunk;
  __syncthreads();
  for (int off = 1; off < 256; off <<= 1) {
    const uint32_t v = (t + off < 256) ? scan[t + off] : 0u;
    __syncthreads();
    scan[t] += v;
    __syncthreads();
  }
  const uint32_t total = scan[0];
  if (total > 128u) {
    const uint32_t Sc = scan[t];
    const uint32_t Sn = (t < 255) ? scan[t + 1] : 0u;
    if (Sc >= 128u && Sn < 128u) {
      uint32_t s = Sn;
      #pragma unroll
      for (int j = 4; j >= 0; --j) {
        const uint32_t h = hist[t * 5 + j];
        if (s + h >= 128u) { s_thr = t * 5 + j; s_take = 128 - (int)s; break; }
        s += h;
      }
    }
  }
  __syncthreads();
  const int thr = s_thr;
  const uint32_t take = (uint32_t)s_take;
  uint32_t lt = 0;
  if (thr > 0) {
    #pragma unroll
    for (int k = 0; k < 16; ++k) lt += (rv[k] == (uint32_t)thr) ? 1u : 0u;
  }
  scan[t] = lt;
  __syncthreads();
  for (int off = 1; off < 256; off <<= 1) {
    const uint32_t v = (t >= off) ? scan[t - off] : 0u;
    __syncthreads();
    scan[t] += v;
    __syncthreads();
  }
  uint32_t run = scan[t] - lt;
  #pragma unroll
  for (int k = 0; k < 16; ++k) {
    bool s;
    if (thr == 0) {
      s = rv[k] > 0u;
    } else {
      s = (rv[k] > (uint32_t)thr);
      if (rv[k] == (uint32_t)thr) { s = (run < take); ++run; }
    }
    buf[lbase + k] = s ? 1u : 0u;
  }
  __syncthreads();
  #pragma unroll
  for (int k = 0; k < 16; ++k) {
    const int li = t + k * 256;
    sel[(size_t)(b * NN + li) * 84] = (int)buf[li];
  }
}

__global__ __launch_bounds__(256) void out_kernel_s(const float* __restrict__ roi,
                                                    const float* __restrict__ gt,
                                                    const int* __restrict__ glab,
                                                    const int* __restrict__ midx,
                                                    const int* __restrict__ sel,
                                                    float* __restrict__ out) {
  __shared__ float4 sdv[256];
  __shared__ int slbl[256];
  const int t = threadIdx.x;
  const int ri0 = blockIdx.x * 256;
  const int i = ri0 + t;
  const int b = i >> 12;
  const int mi = midx[(size_t)i * 84];
  const int sv = sel[(size_t)i * 84];
  float4 dv = {0.f, 0.f, 0.f, 0.f};
  int lbl = -1;
  if (sv) {
    const float4 r = ((const float4*)roi)[i];
    const float4 g = ((const float4*)gt)[b * MM + mi];
    lbl = glab[b * MM + mi];
    dv = compute_delta(r, g);
  }
  sdv[t] = dv;
  slbl[t] = lbl;
  __syncthreads();
  const float4 z = {0.f, 0.f, 0.f, 0.f};
  float4* dbase = (float4*)out + (size_t)ri0 * LL;
  #pragma unroll
  for (int k = 0; k < LL; ++k) {
    const int q = t + k * 256;
    const int r = q / 21;
    const int f = q - r * 21;
    dbase[q] = (f == slbl[r]) ? sdv[r] : z;
  }
  float4* lbase = (float4*)(out + DELTA_ELEMS) + (size_t)ri0 * LL / 4;
  for (int q = t; q < 1344; q += 256) {
    const int e0 = q * 4;
    float4 v;
    const int r0 = e0 / 21;       v.x = ((e0 - r0 * 21) == slbl[r0]) ? 1.f : 0.f;
    const int r1 = (e0 + 1) / 21; v.y = ((e0 + 1 - r1 * 21) == slbl[r1]) ? 1.f : 0.f;
    const int r2 = (e0 + 2) / 21; v.z = ((e0 + 2 - r2 * 21) == slbl[r2]) ? 1.f : 0.f;
    const int r3 = (e0 + 3) / 21; v.w = ((e0 + 3 - r3 * 21) == slbl[r3]) ? 1.f : 0.f;
    lbase[q] = v;
  }
}

extern "C" void kernel_launch(void* const* d_in, const int* in_sizes, int n_in,
                              void* d_out, int out_size, void* d_ws, size_t ws_size,
                              hipStream_t stream) {
  const float* roi = (const float*)d_in[0];
  const float* gt  = (const float*)d_in[1];
  const int* glab  = (const int*)d_in[2];
  float* out = (float*)d_out;

  // Host-side JAX key derivation (foldlike split):
  // key(42)=(0,42); kp=threefry(key,(0,0)); hi=threefry(kp,(0,0)); lo=threefry(kp,(0,1))
  uint32_t kp0, kp1, k1a, k1b, k2a, k2b;
  threefry2x32(0u, 42u, 0u, 0u, &kp0, &kp1);
  threefry2x32(kp0, kp1, 0u, 0u, &k1a, &k1b);
  threefry2x32(kp0, kp1, 0u, 1u, &k2a, &k2b);

  if (d_ws != nullptr && ws_size >= (size_t)NTOT * 4) {
    uint32_t* packed = (uint32_t*)d_ws;
    hipLaunchKernelGGL(iou_zero_pack_kernel, dim3(NN / 256, BB), dim3(256), 0,
                       stream, roi, gt, packed, out, k1a, k1b, k2a, k2b);
    hipLaunchKernelGGL(select_scatter_kernel, dim3(BB), dim3(256), 0, stream,
                       roi, gt, glab, packed, out);
  } else {
    int* midx     = (int*)out;          // slot0 of each 84-float block
    float* merged = out + 1;            // slot1
    int* sel      = (int*)out + 2;      // slot2
    hipLaunchKernelGGL(iou_kernel_s, dim3(NN / 256, BB), dim3(256), 0, stream,
                       roi, gt, midx, merged);
    hipLaunchKernelGGL(select_kernel_s, dim3(BB), dim3(256), 0, stream,
                       merged, sel, k1a, k1b, k2a, k2b);
    hipLaunchKernelGGL(out_kernel_s, dim3(NTOT / 256), dim3(256), 0, stream,
                       roi, gt, glab, midx, sel, out);
  }
}

// Round 14
// 57.511 us; speedup vs baseline: 1.0786x; 1.0786x over previous
//
#include <hip/hip_runtime.h>
#include <stdint.h>

#pragma clang fp contract(off)

// PRNG: jax_threefry_partitionable 32-bit random_bits = o0 ^ o1 (VERIFIED round 3)
// BEST KNOWN = r8 structure (57.5us): K1 iou+pack (4B/roi), K2 per-window
// select-recompute + fused coalesced full write. Neutral/regressing since:
// r9/r10 internals (57.5), r12 occupancy force (60.5), r11 mega (112),
// r13 zero-overlap+scatter (62.0). This round: exact r8 revert.

#define BB 64
#define NN 4096
#define MM 128
#define LL 21
#define NTOT (BB * NN)                           // 262144 rois
#define DELTA_ELEMS ((size_t)BB * NN * LL * 4)   // 22020096 floats

__host__ __device__ __forceinline__ uint32_t rotl32(uint32_t v, int s) {
  return (v << s) | (v >> (32 - s));
}

// Threefry-2x32, 20 rounds (JAX's threefry2x32).
__host__ __device__ inline void threefry2x32(uint32_t k0, uint32_t k1,
                                             uint32_t x0, uint32_t x1,
                                             uint32_t* o0, uint32_t* o1) {
  const uint32_t ks2 = k0 ^ k1 ^ 0x1BD11BDAu;
  x0 += k0; x1 += k1;
#define TF_R(r) do { x0 += x1; x1 = rotl32(x1, (r)); x1 ^= x0; } while (0)
  TF_R(13); TF_R(15); TF_R(26); TF_R(6);
  x0 += k1;  x1 += ks2 + 1u;
  TF_R(17); TF_R(29); TF_R(16); TF_R(24);
  x0 += ks2; x1 += k0 + 2u;
  TF_R(13); TF_R(15); TF_R(26); TF_R(6);
  x0 += k0;  x1 += k1 + 3u;
  TF_R(17); TF_R(29); TF_R(16); TF_R(24);
  x0 += k1;  x1 += ks2 + 4u;
  TF_R(13); TF_R(15); TF_R(26); TF_R(6);
  x0 += ks2; x1 += k0 + 5u;
#undef TF_R
  *o0 = x0; *o1 = x1;
}

__device__ __forceinline__ uint32_t jax_bits32(uint32_t ka, uint32_t kb, uint32_t idx) {
  uint32_t o0, o1;
  threefry2x32(ka, kb, 0u, idx, &o0, &o1);   // counter (hi=0, lo=idx)
  return o0 ^ o1;                            // partitionable 32-bit fold
}

// jax.random.randint(key, (B,N), 1, 1280): span=1279, mult=(2^16%1279)^2%1279=882
__device__ __forceinline__ uint32_t jax_randint_1_1280(uint32_t k1a, uint32_t k1b,
                                                       uint32_t k2a, uint32_t k2b,
                                                       uint32_t idx) {
  const uint32_t hi = jax_bits32(k1a, k1b, idx);
  const uint32_t lo = jax_bits32(k2a, k2b, idx);
  const uint32_t off = ((hi % 1279u) * 882u + (lo % 1279u)) % 1279u;
  return 1u + off;
}

__device__ __forceinline__ float4 compute_delta(const float4 r, const float4 g) {
  float bh = r.z - r.x, bw = r.w - r.y;
  const float bcy = r.x + 0.5f * bh, bcx = r.y + 0.5f * bw;
  const float gh = g.z - g.x, gw = g.w - g.y;
  const float gcy = g.x + 0.5f * gh, gcx = g.y + 0.5f * gw;
  if (bw == 0.0f) bw = 1e-3f;
  if (bh == 0.0f) bh = 1e-3f;
  const float dx = (gcx - bcx) / bw;
  const float dy = (gcy - bcy) / bh;
  const float dw = (gw == 0.0f) ? 0.0f : logf(gw / bw);
  const float dh = (gh == 0.0f) ? 0.0f : logf(gh / bh);
  float4 dv;
  dv.x = dy / 0.1f; dv.y = dx / 0.1f; dv.z = dh / 0.2f; dv.w = dw / 0.2f;
  return dv;
}

// ---------- K1: IoU argmax + randint, packed to 4B/roi ----------
// pk = midx(7b) | rand<<7 (rand=0 iff merged<=0.5; rand in [1,1279] fits 11b)
__global__ __launch_bounds__(256) void iou_pack_kernel(
    const float* __restrict__ roi, const float* __restrict__ gt,
    uint32_t* __restrict__ packed,
    uint32_t k1a, uint32_t k1b, uint32_t k2a, uint32_t k2b) {
  __shared__ float4 gtb[MM];
  __shared__ float gar[MM];
  const int b = blockIdx.y;
  const int t = threadIdx.x;
  if (t < MM) {
    const float4 g = ((const float4*)gt)[b * MM + t];
    gtb[t] = g;
    gar[t] = (g.z - g.x) * (g.w - g.y);
  }
  __syncthreads();
  const int i = b * NN + blockIdx.x * 256 + t;
  const float4 r = ((const float4*)roi)[i];           // [y1,x1,y2,x2]
  const float barea = (r.z - r.x) * (r.w - r.y);
  float best = -1.0f;
  int bm = 0;
  for (int m = 0; m < MM; ++m) {
    const float4 g = gtb[m];
    const float xt = fmaxf(r.y, g.y);
    const float yt = fmaxf(r.x, g.x);
    const float xb = fminf(r.w, g.w);
    const float yb = fminf(r.z, g.z);
    const float inter = fmaxf(xb - xt, 0.0f) * fmaxf(yb - yt, 0.0f);
    const float uni = (barea + gar[m]) - inter;
    const float iou = inter / uni;                    // IEEE div, bit-exact vs ref
    if (iou > best) { best = iou; bm = m; }           // first-occurrence argmax
  }
  const uint32_t rnd = jax_randint_1_1280(k1a, k1b, k2a, k2b, (uint32_t)i);
  packed[i] = (uint32_t)bm | ((best > 0.5f) ? (rnd << 7) : 0u);
}

// ---------- K2: per-window select-recompute + fused coalesced write ----------
// 16 blocks per row; each re-derives the row's thr/take/tie-ranks from packed
// (identical deterministic result), then writes its 256-roi output region.
__global__ __launch_bounds__(256) void fused_out_kernel(
    const float* __restrict__ roi, const float* __restrict__ gt,
    const int* __restrict__ glab, const uint32_t* __restrict__ packed,
    float* __restrict__ out) {
  __shared__ uint32_t hist[1280];
  __shared__ uint32_t scan[256];
  __shared__ unsigned char selb[NN];    // row-wide selection bits (bytes)
  __shared__ float4 sdv[256];
  __shared__ int slbl[256];
  __shared__ int s_thr;
  __shared__ int s_take;
  const int br = blockIdx.x;
  const int b = br >> 4;                // row
  const int win0 = (br & 15) << 8;      // this block's 256-roi window in the row
  const int t = threadIdx.x;
  for (int j = t; j < 1280; j += 256) hist[j] = 0u;
  if (t == 0) { s_thr = 0; s_take = 0; }
  __syncthreads();

  // Phase B: thread t owns rois t*16..t*16+15 of the ROW (tie order!)
  uint32_t rv[16];
  const uint4* p4 = (const uint4*)(packed + (size_t)b * NN);
  #pragma unroll
  for (int q = 0; q < 4; ++q) {
    const uint4 w = p4[t * 4 + q];
    rv[q * 4 + 0] = w.x >> 7;
    rv[q * 4 + 1] = w.y >> 7;
    rv[q * 4 + 2] = w.z >> 7;
    rv[q * 4 + 3] = w.w >> 7;
  }
  #pragma unroll
  for (int k = 0; k < 16; ++k)
    if (rv[k]) atomicAdd(&hist[rv[k]], 1u);
  __syncthreads();

  // Phase C: suffix sums over 5-bin chunks -> threshold bin + take count
  uint32_t chunk = 0;
  #pragma unroll
  for (int j = 0; j < 5; ++j) chunk += hist[t * 5 + j];
  scan[t] = chunk;
  __syncthreads();
  for (int off = 1; off < 256; off <<= 1) {
    const uint32_t v = (t + off < 256) ? scan[t + off] : 0u;
    __syncthreads();
    scan[t] += v;
    __syncthreads();
  }
  const uint32_t total = scan[0];
  if (total > 128u) {
    const uint32_t Sc = scan[t];
    const uint32_t Sn = (t < 255) ? scan[t + 1] : 0u;
    if (Sc >= 128u && Sn < 128u) {
      uint32_t s = Sn;
      #pragma unroll
      for (int j = 4; j >= 0; --j) {
        const uint32_t h = hist[t * 5 + j];
        if (s + h >= 128u) { s_thr = t * 5 + j; s_take = 128 - (int)s; break; }
        s += h;
      }
    }
  }
  __syncthreads();
  const uint32_t thr = (uint32_t)s_thr;
  const uint32_t take = (uint32_t)s_take;

  // Phase D: exclusive prefix of tie counts (ascending index), then sel bits
  uint32_t lt = 0;
  if (thr > 0) {
    #pragma unroll
    for (int k = 0; k < 16; ++k) lt += (rv[k] == thr) ? 1u : 0u;
  }
  scan[t] = lt;
  __syncthreads();
  for (int off = 1; off < 256; off <<= 1) {
    const uint32_t v = (t >= off) ? scan[t - off] : 0u;
    __syncthreads();
    scan[t] += v;
    __syncthreads();
  }
  uint32_t run = scan[t] - lt;
  uint32_t sw0 = 0, sw1 = 0, sw2 = 0, sw3 = 0;
  #pragma unroll
  for (int k = 0; k < 16; ++k) {
    bool s;
    if (thr == 0) {
      s = rv[k] > 0u;
    } else {
      s = (rv[k] > thr);
      if (rv[k] == thr) { s = (run < take); ++run; }
    }
    const uint32_t bit = s ? 1u : 0u;
    if (k < 4)       sw0 |= bit << (k * 8);
    else if (k < 8)  sw1 |= bit << ((k - 4) * 8);
    else if (k < 12) sw2 |= bit << ((k - 8) * 8);
    else             sw3 |= bit << ((k - 12) * 8);
  }
  ((uint4*)selb)[t] = make_uint4(sw0, sw1, sw2, sw3);
  __syncthreads();

  // Phase E: this window's per-roi delta/label, then coalesced region write
  const int irow = win0 + t;
  const int i = b * NN + irow;
  float4 dv = {0.f, 0.f, 0.f, 0.f};
  int lbl = -1;
  if (selb[irow]) {
    const int mi = (int)(packed[i] & 127u);
    const float4 r = ((const float4*)roi)[i];
    const float4 g = ((const float4*)gt)[b * MM + mi];
    lbl = glab[b * MM + mi];
    dv = compute_delta(r, g);
  }
  sdv[t] = dv;
  slbl[t] = lbl;
  __syncthreads();
  const float4 z = {0.f, 0.f, 0.f, 0.f};
  const size_t ri0 = (size_t)b * NN + win0;
  float4* dbase = (float4*)out + ri0 * LL;      // 5376 float4 region
  #pragma unroll
  for (int k = 0; k < LL; ++k) {
    const int q = t + k * 256;
    const int r = q / 21;
    const int f = q - r * 21;
    dbase[q] = (f == slbl[r]) ? sdv[r] : z;
  }
  float4* lbase = (float4*)(out + DELTA_ELEMS) + ri0 * LL / 4;  // 1344 float4
  for (int q = t; q < 1344; q += 256) {
    const int e0 = q * 4;
    float4 v;
    const int r0 = e0 / 21;       v.x = ((e0 - r0 * 21) == slbl[r0]) ? 1.f : 0.f;
    const int r1 = (e0 + 1) / 21; v.y = ((e0 + 1 - r1 * 21) == slbl[r1]) ? 1.f : 0.f;
    const int r2 = (e0 + 2) / 21; v.z = ((e0 + 2 - r2 * 21) == slbl[r2]) ? 1.f : 0.f;
    const int r3 = (e0 + 3) / 21; v.w = ((e0 + 3 - r3 * 21) == slbl[r3]) ? 1.f : 0.f;
    lbase[q] = v;
  }
}

// ================= Slots-mode fallback (r4 proven, ws too small) =================
__global__ __launch_bounds__(256) void iou_kernel_s(const float* __restrict__ roi,
                                                    const float* __restrict__ gt,
                                                    int* __restrict__ midx,
                                                    float* __restrict__ merged) {
  __shared__ float4 gtb[MM];
  __shared__ float gar[MM];
  const int b = blockIdx.y;
  const int t = threadIdx.x;
  if (t < MM) {
    const float4 g = ((const float4*)gt)[b * MM + t];
    gtb[t] = g;
    gar[t] = (g.z - g.x) * (g.w - g.y);
  }
  __syncthreads();
  const int i = b * NN + blockIdx.x * 256 + t;
  const float4 r = ((const float4*)roi)[i];
  const float barea = (r.z - r.x) * (r.w - r.y);
  float best = -1.0f;
  int bm = 0;
  for (int m = 0; m < MM; ++m) {
    const float4 g = gtb[m];
    const float xt = fmaxf(r.y, g.y);
    const float yt = fmaxf(r.x, g.x);
    const float xb = fminf(r.w, g.w);
    const float yb = fminf(r.z, g.z);
    const float inter = fmaxf(xb - xt, 0.0f) * fmaxf(yb - yt, 0.0f);
    const float iou = inter / ((barea + gar[m]) - inter);
    if (iou > best) { best = iou; bm = m; }
  }
  midx[(size_t)i * 84] = bm;
  merged[(size_t)i * 84] = best;
}

__global__ __launch_bounds__(256) void select_kernel_s(const float* __restrict__ merged,
                                                       int* __restrict__ sel,
                                                       uint32_t k1a, uint32_t k1b,
                                                       uint32_t k2a, uint32_t k2b) {
  __shared__ uint32_t buf[NN];
  __shared__ uint32_t hist[1280];
  __shared__ uint32_t scan[256];
  __shared__ int s_thr;
  __shared__ int s_take;
  const int b = blockIdx.x;
  const int t = threadIdx.x;
  for (int j = t; j < 1280; j += 256) hist[j] = 0u;
  if (t == 0) { s_thr = 0; s_take = 0; }
  #pragma unroll
  for (int k = 0; k < 16; ++k) {
    const int li = t + k * 256;
    buf[li] = __float_as_uint(merged[(size_t)(b * NN + li) * 84]);
  }
  __syncthreads();
  uint32_t rv[16];
  const int lbase = t * 16;
  #pragma unroll
  for (int k = 0; k < 16; ++k) {
    const int li = lbase + k;
    uint32_t r = 0u;
    if (__uint_as_float(buf[li]) > 0.5f) {
      r = jax_randint_1_1280(k1a, k1b, k2a, k2b, (uint32_t)(b * NN + li));
      atomicAdd(&hist[r], 1u);
    }
    rv[k] = r;
  }
  __syncthreads();
  uint32_t chunk = 0;
  #pragma unroll
  for (int j = 0; j < 5; ++j) chunk += hist[t * 5 + j];
  scan[t] = chunk;
  __syncthreads();
  for (int off = 1; off < 256; off <<= 1) {
    const uint32_t v = (t + off < 256) ? scan[t + off] : 0u;
    __syncthreads();
    scan[t] += v;
    __syncthreads();
  }
  const uint32_t total = scan[0];
  if (total > 128u) {
    const uint32_t Sc = scan[t];
    const uint32_t Sn = (t < 255) ? scan[t + 1] : 0u;
    if (Sc >= 128u && Sn < 128u) {
      uint32_t s = Sn;
      #pragma unroll
      for (int j = 4; j >= 0; --j) {
        const uint32_t h = hist[t * 5 + j];
        if (s + h >= 128u) { s_thr = t * 5 + j; s_take = 128 - (int)s; break; }
        s += h;
      }
    }
  }
  __syncthreads();
  const int thr = s_thr;
  const uint32_t take = (uint32_t)s_take;
  uint32_t lt = 0;
  if (thr > 0) {
    #pragma unroll
    for (int k = 0; k < 16; ++k) lt += (rv[k] == (uint32_t)thr) ? 1u : 0u;
  }
  scan[t] = lt;
  __syncthreads();
  for (int off = 1; off < 256; off <<= 1) {
    const uint32_t v = (t >= off) ? scan[t - off] : 0u;
    __syncthreads();
    scan[t] += v;
    __syncthreads();
  }
  uint32_t run = scan[t] - lt;
  #pragma unroll
  for (int k = 0; k < 16; ++k) {
    bool s;
    if (thr == 0) {
      s = rv[k] > 0u;
    } else {
      s = (rv[k] > (uint32_t)thr);
      if (rv[k] == (uint32_t)thr) { s = (run < take); ++run; }
    }
    buf[lbase + k] = s ? 1u : 0u;
  }
  __syncthreads();
  #pragma unroll
  for (int k = 0; k < 16; ++k) {
    const int li = t + k * 256;
    sel[(size_t)(b * NN + li) * 84] = (int)buf[li];
  }
}

__global__ __launch_bounds__(256) void out_kernel_s(const float* __restrict__ roi,
                                                    const float* __restrict__ gt,
                                                    const int* __restrict__ glab,
                                                    const int* __restrict__ midx,
                                                    const int* __restrict__ sel,
                                                    float* __restrict__ out) {
  __shared__ float4 sdv[256];
  __shared__ int slbl[256];
  const int t = threadIdx.x;
  const int ri0 = blockIdx.x * 256;
  const int i = ri0 + t;
  const int b = i >> 12;
  const int mi = midx[(size_t)i * 84];
  const int sv = sel[(size_t)i * 84];
  float4 dv = {0.f, 0.f, 0.f, 0.f};
  int lbl = -1;
  if (sv) {
    const float4 r = ((const float4*)roi)[i];
    const float4 g = ((const float4*)gt)[b * MM + mi];
    lbl = glab[b * MM + mi];
    dv = compute_delta(r, g);
  }
  sdv[t] = dv;
  slbl[t] = lbl;
  __syncthreads();
  const float4 z = {0.f, 0.f, 0.f, 0.f};
  float4* dbase = (float4*)out + (size_t)ri0 * LL;
  #pragma unroll
  for (int k = 0; k < LL; ++k) {
    const int q = t + k * 256;
    const int r = q / 21;
    const int f = q - r * 21;
    dbase[q] = (f == slbl[r]) ? sdv[r] : z;
  }
  float4* lbase = (float4*)(out + DELTA_ELEMS) + (size_t)ri0 * LL / 4;
  for (int q = t; q < 1344; q += 256) {
    const int e0 = q * 4;
    float4 v;
    const int r0 = e0 / 21;       v.x = ((e0 - r0 * 21) == slbl[r0]) ? 1.f : 0.f;
    const int r1 = (e0 + 1) / 21; v.y = ((e0 + 1 - r1 * 21) == slbl[r1]) ? 1.f : 0.f;
    const int r2 = (e0 + 2) / 21; v.z = ((e0 + 2 - r2 * 21) == slbl[r2]) ? 1.f : 0.f;
    const int r3 = (e0 + 3) / 21; v.w = ((e0 + 3 - r3 * 21) == slbl[r3]) ? 1.f : 0.f;
    lbase[q] = v;
  }
}

extern "C" void kernel_launch(void* const* d_in, const int* in_sizes, int n_in,
                              void* d_out, int out_size, void* d_ws, size_t ws_size,
                              hipStream_t stream) {
  const float* roi = (const float*)d_in[0];
  const float* gt  = (const float*)d_in[1];
  const int* glab  = (const int*)d_in[2];
  float* out = (float*)d_out;

  // Host-side JAX key derivation (foldlike split):
  // key(42)=(0,42); kp=threefry(key,(0,0)); hi=threefry(kp,(0,0)); lo=threefry(kp,(0,1))
  uint32_t kp0, kp1, k1a, k1b, k2a, k2b;
  threefry2x32(0u, 42u, 0u, 0u, &kp0, &kp1);
  threefry2x32(kp0, kp1, 0u, 0u, &k1a, &k1b);
  threefry2x32(kp0, kp1, 0u, 1u, &k2a, &k2b);

  if (d_ws != nullptr && ws_size >= (size_t)NTOT * 4) {
    uint32_t* packed = (uint32_t*)d_ws;
    hipLaunchKernelGGL(iou_pack_kernel, dim3(NN / 256, BB), dim3(256), 0, stream,
                       roi, gt, packed, k1a, k1b, k2a, k2b);
    hipLaunchKernelGGL(fused_out_kernel, dim3(NTOT / 256), dim3(256), 0, stream,
                       roi, gt, glab, packed, out);
  } else {
    int* midx     = (int*)out;          // slot0 of each 84-float block
    float* merged = out + 1;            // slot1
    int* sel      = (int*)out + 2;      // slot2
    hipLaunchKernelGGL(iou_kernel_s, dim3(NN / 256, BB), dim3(256), 0, stream,
                       roi, gt, midx, merged);
    hipLaunchKernelGGL(select_kernel_s, dim3(BB), dim3(256), 0, stream,
                       merged, sel, k1a, k1b, k2a, k2b);
    hipLaunchKernelGGL(out_kernel_s, dim3(NTOT / 256), dim3(256), 0, stream,
                       roi, gt, glab, midx, sel, out);
  }
}